// Round 8
// baseline (1169.388 us; speedup 1.0000x reference)
//
#include <hip/hip_runtime.h>

#define NPTS 65552          // 16 * (64*64 + 1)
#define MPAD 65664          // 513 * 128
#define NVOX 274625         // 65^3

typedef unsigned short u16;
typedef __attribute__((ext_vector_type(8))) short bf16x8;
typedef __attribute__((ext_vector_type(4))) float f32x4;
typedef __attribute__((ext_vector_type(4))) unsigned short us4;

__device__ __forceinline__ u16 f2bf(float f) {
  unsigned int u = __float_as_uint(f);
  return (u16)((u + 0x7FFFu + ((u >> 16) & 1u)) >> 16);
}

// ---------------- coords from depth ----------------
__global__ void coords_kernel(const float* __restrict__ depth, int* __restrict__ pcoord) {
  int b = blockIdx.x, tid = threadIdx.x;
  const float* d = depth + b * 4096;
  float mn = 1e30f, mx = -1e30f;
  for (int p = tid; p < 4096; p += 256) {
    float v = d[p];
    mn = fminf(mn, v);
    mx = fmaxf(mx, v);
  }
  __shared__ float smn[256], smx[256];
  smn[tid] = mn; smx[tid] = mx;
  __syncthreads();
  for (int s = 128; s > 0; s >>= 1) {
    if (tid < s) {
      smn[tid] = fminf(smn[tid], smn[tid + s]);
      smx[tid] = fmaxf(smx[tid], smx[tid + s]);
    }
    __syncthreads();
  }
  mn = smn[0]; mx = smx[0];
  float den = mx - mn + 1e-8f;
  for (int p = tid; p < 4096; p += 256) {
    int i = p >> 6, j = p & 63;
    float x = (float)j / 63.0f;       // matches jnp arange/63 (IEEE div)
    float y = (float)i / 63.0f;
    float z = (d[p] - mn) / den;
    int cx = (int)rintf(x * 64.0f);   // *64 exact, rintf = round-half-even
    int cy = (int)rintf(y * 64.0f);
    int cz = (int)rintf(z * 64.0f);
    cx = min(max(cx, 0), 64); cy = min(max(cy, 0), 64); cz = min(max(cz, 0), 64);
    pcoord[b * 4097 + 1 + p] = cx | (cy << 8) | (cz << 16);
  }
  if (tid == 0) pcoord[b * 4097] = 0;   // cls token coord (0,0,0)
}

// ---------------- voxel map ----------------
__global__ void init_idx(int* __restrict__ m) {
  int i = blockIdx.x * 256 + threadIdx.x;
  if (i < NVOX) m[i] = -1;
}

__global__ void scatter_idx(const int* __restrict__ pcoord, int* __restrict__ m) {
  int n = blockIdx.x * 256 + threadIdx.x;
  if (n >= NPTS) return;
  int c = pcoord[n];
  int lin = ((c & 255) * 65 + ((c >> 8) & 255)) * 65 + ((c >> 16) & 255);
  atomicMax(&m[lin], n);
}

// ---------------- neighbor ids: nid[k][n], invalid -> NPTS (zero row) ----------------
__global__ void nbr_kernel(const int* __restrict__ pcoord, const int* __restrict__ m,
                           int* __restrict__ nid) {
  int n = blockIdx.x * 256 + threadIdx.x;
  if (n >= MPAD) return;
  if (n >= NPTS) {
    for (int k = 0; k < 27; ++k) nid[k * MPAD + n] = NPTS;
    return;
  }
  int c = pcoord[n];
  int cx = c & 255, cy = (c >> 8) & 255, cz = (c >> 16) & 255;
#pragma unroll
  for (int k = 0; k < 27; ++k) {
    int nx = cx + k / 9 - 1;
    int ny = cy + (k / 3) % 3 - 1;
    int nz = cz + k % 3 - 1;
    int id = NPTS;
    if (((unsigned)nx <= 64u) && ((unsigned)ny <= 64u) && ((unsigned)nz <= 64u)) {
      int v = m[(nx * 65 + ny) * 65 + nz];
      if (v >= 0) id = v;
    }
    nid[k * MPAD + n] = id;
  }
}

// ---------------- features fp32 -> bf16 (+ zero row at NPTS) ----------------
__global__ void conv_feat(const float* __restrict__ f, u16* __restrict__ o) {
  int q = blockIdx.x * 256 + threadIdx.x;       // quad index
  if (q >= (NPTS + 1) * 64) return;
  us4 r;
  if (q < NPTS * 64) {
    float4 v = ((const float4*)f)[q];
    r.x = f2bf(v.x); r.y = f2bf(v.y); r.z = f2bf(v.z); r.w = f2bf(v.w);
  } else {
    r.x = 0; r.y = 0; r.z = 0; r.w = 0;
  }
  ((us4*)o)[q] = r;
}

// -------- weight fp32 [27][ci][co] -> bf16 wt2[step(216)][kchunk(4)][co(256)][8]
__global__ void conv_wt2(const float* __restrict__ w, u16* __restrict__ wt2) {
  int u = blockIdx.x * 256 + threadIdx.x;       // < 27*65536
  int e = u & 7, row = (u >> 3) & 255, lk = (u >> 11) & 3, ks = (u >> 13) & 7, ko = u >> 16;
  int ci = ks * 32 + lk * 8 + e;
  wt2[u] = f2bf(w[ko * 65536 + ci * 256 + row]);
}

// ---------------- gather-GEMM: out[N,256] = sum_k gather(feat, nid_k) @ W_k ----------------
__device__ __forceinline__ void gload16(const void* g, unsigned int lds_off) {
  __builtin_amdgcn_global_load_lds(
      (__attribute__((address_space(1))) void*)(size_t)g,
      (__attribute__((address_space(3))) void*)(unsigned int)lds_off,
      16, 0, 0);
}

// One pipeline step. Frags for step t are read into na/nb while the MFMA
// cluster consumes pa/pb (step t-1's frags) -> ds_read latency hides under MFMA.
#define STEP(DONID, LASTKO, KS, DOMFMA)                                       \
  {                                                                           \
    if ((LASTKO) && (KS) == 7)                                                \
      asm volatile("s_waitcnt vmcnt(0)" ::: "memory");                        \
    else if ((KS) == 1 && !(LASTKO))                                          \
      asm volatile("s_waitcnt vmcnt(4)" ::: "memory");                        \
    else                                                                      \
      asm volatile("s_waitcnt vmcnt(3)" ::: "memory");                        \
    __builtin_amdgcn_s_barrier();                                             \
    if (DONID) nv_next = nid[(koRT + 1) * MPAD + gmA];                        \
    if (!((LASTKO) && (KS) >= 6)) {                                           \
      int snv = ((KS) >= 6) ? nv_next : nv;                                   \
      gload16(featc + ((size_t)snv << 9) + ((((KS) + 2) & 7) << 6) + cA16,    \
              A0 + a2 + (w << 10));                                           \
      const char* bs = wtc + ((size_t)(koRT * 8 + (KS) + 2) << 14) + bSrcW;   \
      gload16(bs, B0 + b2 + (w << 11));                                       \
      gload16(bs + 1024, B0 + b2 + (w << 11) + 1024);                         \
    }                                                                         \
    const bf16x8* Av = (const bf16x8*)(Asc + a0);                             \
    const bf16x8* Bv = (const bf16x8*)(Bsc + b0);                             \
    bf16x8 na[4], nb[4];                                                      \
    _Pragma("unroll") for (int mm = 0; mm < 4; ++mm)                          \
        na[mm] = Av[(((wr << 6) + (mm << 4) + lm) << 2) + aswz];              \
    _Pragma("unroll") for (int nn = 0; nn < 4; ++nn)                          \
        nb[nn] = Bv[(lk << 8) + (wc << 6) + (nn << 4) + lm];                  \
    if (DOMFMA) {                                                             \
      __builtin_amdgcn_s_setprio(1);                                          \
      _Pragma("unroll") for (int mm = 0; mm < 4; ++mm)                        \
          _Pragma("unroll") for (int nn = 0; nn < 4; ++nn)                    \
              acc[mm][nn] = __builtin_amdgcn_mfma_f32_16x16x32_bf16(          \
                  pa[mm], pb[nn], acc[mm][nn], 0, 0, 0);                      \
      __builtin_amdgcn_s_setprio(0);                                          \
    }                                                                         \
    _Pragma("unroll") for (int mm = 0; mm < 4; ++mm) {                        \
      pa[mm] = na[mm]; pb[mm] = nb[mm];                                       \
    }                                                                         \
    asm volatile("s_waitcnt lgkmcnt(0)" ::: "memory");                        \
    { unsigned t_ = a0; a0 = a1; a1 = a2; a2 = t_; }                          \
    { unsigned t_ = b0; b0 = b1; b1 = b2; b2 = t_; }                          \
  }

__global__ __launch_bounds__(512, 4) void gemm_kernel(const u16* __restrict__ feat,
                                                      const u16* __restrict__ wt,
                                                      const int* __restrict__ nid,
                                                      float* __restrict__ out) {
  __shared__ u16 As[3 * 4096];   // per buf 8KB: [row(128)][slot(4)][8e] (XOR-swizzled)
  __shared__ u16 Bs[3 * 8192];   // per buf 16KB: [kchunk(4)][co(256)][8e]
  int bm = blockIdx.x;
  int tid = threadIdx.x;
  int w = tid >> 6, l = tid & 63;
  int wr = w >> 2, wc = w & 3;     // wave tile (wr*64, wc*64)
  int lm = l & 15, lk = l >> 4;

  unsigned A0 = (unsigned)(size_t)&As[0];
  unsigned B0 = (unsigned)(size_t)&Bs[0];
  const char* Asc = (const char*)&As[0];
  const char* Bsc = (const char*)&Bs[0];

  const char* featc = (const char*)feat;
  const char* wtc = (const char*)wt;

  // A staging: 4 lanes per row (coalesced 64B), XOR chunk swizzle on source
  int row_l = (w << 4) + (l >> 2);
  int gmA = bm * 128 + row_l;
  int cA16 = (((l & 3) ^ ((row_l >> 1) & 3)) << 4);
  size_t bSrcW = (size_t)((w << 11) + (l << 4));  // per-lane B source byte offset
  // A ds_read swizzle
  int aswz = lk ^ ((lm >> 1) & 3);

  f32x4 acc[4][4];
#pragma unroll
  for (int m = 0; m < 4; ++m)
#pragma unroll
    for (int n = 0; n < 4; ++n) acc[m][n] = (f32x4){0.f, 0.f, 0.f, 0.f};

  int nv = nid[gmA];                // ko=0 gather row
  int nv_next = nv;

  // prologue: stage steps 0,1 into bufs 0,1 (both ko=0)
  {
    gload16(featc + ((size_t)nv << 9) + cA16, A0 + (w << 10));
    const char* bs0 = wtc + bSrcW;
    gload16(bs0, B0 + (w << 11));
    gload16(bs0 + 1024, B0 + (w << 11) + 1024);
    gload16(featc + ((size_t)nv << 9) + 64 + cA16, A0 + 8192 + (w << 10));
    const char* bs1 = wtc + 16384 + bSrcW;
    gload16(bs1, B0 + 16384 + (w << 11));
    gload16(bs1 + 1024, B0 + 16384 + (w << 11) + 1024);
  }

  unsigned a0 = 0, a1 = 8192, a2 = 16384;       // A buf byte offsets
  unsigned b0 = 0, b1 = 16384, b2 = 32768;      // B buf byte offsets

  bf16x8 pa[4], pb[4];

  // ---- ko = 0 (first step primes pa/pb, no MFMA) ----
  int koRT = 0;
  {
    STEP(true,  false, 0, false);
    STEP(false, false, 1, true);
    STEP(false, false, 2, true);
    STEP(false, false, 3, true);
    STEP(false, false, 4, true);
    STEP(false, false, 5, true);
    STEP(false, false, 6, true);
    STEP(false, false, 7, true);
    nv = nv_next;
  }
  // ---- ko = 1 .. 25 ----
  for (koRT = 1; koRT < 26; ++koRT) {
    STEP(true,  false, 0, true);
    STEP(false, false, 1, true);
    STEP(false, false, 2, true);
    STEP(false, false, 3, true);
    STEP(false, false, 4, true);
    STEP(false, false, 5, true);
    STEP(false, false, 6, true);
    STEP(false, false, 7, true);
    nv = nv_next;
  }
  // ---- ko = 26 (no nid prefetch; staging stops at ks=5; final drain at ks=7) ----
  koRT = 26;
  {
    STEP(false, true, 0, true);
    STEP(false, true, 1, true);
    STEP(false, true, 2, true);
    STEP(false, true, 3, true);
    STEP(false, true, 4, true);
    STEP(false, true, 5, true);
    STEP(false, true, 6, true);
    STEP(false, true, 7, true);
  }
  // final MFMA cluster on step 215's fragments
  {
    __builtin_amdgcn_s_setprio(1);
#pragma unroll
    for (int m = 0; m < 4; ++m)
#pragma unroll
      for (int n = 0; n < 4; ++n)
        acc[m][n] = __builtin_amdgcn_mfma_f32_16x16x32_bf16(pa[m], pb[n], acc[m][n], 0, 0, 0);
    __builtin_amdgcn_s_setprio(0);
  }

  // epilogue: D row = (lk*4+i), col = lm within each 16x16 frag
#pragma unroll
  for (int m = 0; m < 4; ++m) {
#pragma unroll
    for (int i = 0; i < 4; ++i) {
      int gr2 = bm * 128 + (wr << 6) + (m << 4) + (lk << 2) + i;
      if (gr2 < NPTS) {
        float* po = out + (size_t)gr2 * 256 + (wc << 6) + lm;
#pragma unroll
        for (int n = 0; n < 4; ++n) po[n << 4] = acc[m][n][i];
      }
    }
  }
}

extern "C" void kernel_launch(void* const* d_in, const int* in_sizes, int n_in,
                              void* d_out, int out_size, void* d_ws, size_t ws_size,
                              hipStream_t stream) {
  const float* features = (const float*)d_in[0];
  const float* depth = (const float*)d_in[1];
  const float* weight = (const float*)d_in[2];
  float* out = (float*)d_out;
  char* ws = (char*)d_ws;

  // ws layout (256B aligned)
  int* idx_map = (int*)(ws + 0);              // 274625 ints
  int* pcoord  = (int*)(ws + 1098752);        // 65552 ints
  int* nid     = (int*)(ws + 1361152);        // 27*65664 ints
  u16* feat_bf = (u16*)(ws + 8452864);        // (65552+1)*256 bf16
  u16* wt_bf   = (u16*)(ws + 42016256);       // 27*65536 bf16 (pre-arranged)
  // total ~45.6 MB

  coords_kernel<<<16, 256, 0, stream>>>(depth, pcoord);
  init_idx<<<(NVOX + 255) / 256, 256, 0, stream>>>(idx_map);
  scatter_idx<<<(NPTS + 255) / 256, 256, 0, stream>>>(pcoord, idx_map);
  nbr_kernel<<<(MPAD + 255) / 256, 256, 0, stream>>>(pcoord, idx_map, nid);
  conv_feat<<<((NPTS + 1) * 64 + 255) / 256, 256, 0, stream>>>(features, feat_bf);
  conv_wt2<<<27 * 65536 / 256, 256, 0, stream>>>(weight, wt_bf);
  gemm_kernel<<<513, 512, 0, stream>>>(feat_bf, wt_bf, nid, out);
}

// Round 9
// 286.355 us; speedup vs baseline: 4.0837x; 4.0837x over previous
//
#include <hip/hip_runtime.h>

#define NPTS 65552          // 16 * (64*64 + 1)
#define MPAD 65664          // 513 * 128
#define NVOX 274625         // 65^3

typedef unsigned short u16;
typedef __attribute__((ext_vector_type(8))) short bf16x8;
typedef __attribute__((ext_vector_type(4))) float f32x4;
typedef __attribute__((ext_vector_type(4))) unsigned short us4;

__device__ __forceinline__ u16 f2bf(float f) {
  unsigned int u = __float_as_uint(f);
  return (u16)((u + 0x7FFFu + ((u >> 16) & 1u)) >> 16);
}

// ---------------- coords from depth ----------------
__global__ void coords_kernel(const float* __restrict__ depth, int* __restrict__ pcoord) {
  int b = blockIdx.x, tid = threadIdx.x;
  const float* d = depth + b * 4096;
  float mn = 1e30f, mx = -1e30f;
  for (int p = tid; p < 4096; p += 256) {
    float v = d[p];
    mn = fminf(mn, v);
    mx = fmaxf(mx, v);
  }
  __shared__ float smn[256], smx[256];
  smn[tid] = mn; smx[tid] = mx;
  __syncthreads();
  for (int s = 128; s > 0; s >>= 1) {
    if (tid < s) {
      smn[tid] = fminf(smn[tid], smn[tid + s]);
      smx[tid] = fmaxf(smx[tid], smx[tid + s]);
    }
    __syncthreads();
  }
  mn = smn[0]; mx = smx[0];
  float den = mx - mn + 1e-8f;
  for (int p = tid; p < 4096; p += 256) {
    int i = p >> 6, j = p & 63;
    float x = (float)j / 63.0f;       // matches jnp arange/63 (IEEE div)
    float y = (float)i / 63.0f;
    float z = (d[p] - mn) / den;
    int cx = (int)rintf(x * 64.0f);   // *64 exact, rintf = round-half-even
    int cy = (int)rintf(y * 64.0f);
    int cz = (int)rintf(z * 64.0f);
    cx = min(max(cx, 0), 64); cy = min(max(cy, 0), 64); cz = min(max(cz, 0), 64);
    pcoord[b * 4097 + 1 + p] = cx | (cy << 8) | (cz << 16);
  }
  if (tid == 0) pcoord[b * 4097] = 0;   // cls token coord (0,0,0)
}

// ---------------- voxel map ----------------
__global__ void init_idx(int* __restrict__ m) {
  int i = blockIdx.x * 256 + threadIdx.x;
  if (i < NVOX) m[i] = -1;
}

__global__ void scatter_idx(const int* __restrict__ pcoord, int* __restrict__ m) {
  int n = blockIdx.x * 256 + threadIdx.x;
  if (n >= NPTS) return;
  int c = pcoord[n];
  int lin = ((c & 255) * 65 + ((c >> 8) & 255)) * 65 + ((c >> 16) & 255);
  atomicMax(&m[lin], n);
}

// ---------------- neighbor ids: nid[k][n], invalid -> NPTS (zero row) ----------------
__global__ void nbr_kernel(const int* __restrict__ pcoord, const int* __restrict__ m,
                           int* __restrict__ nid) {
  int n = blockIdx.x * 256 + threadIdx.x;
  if (n >= MPAD) return;
  if (n >= NPTS) {
    for (int k = 0; k < 27; ++k) nid[k * MPAD + n] = NPTS;
    return;
  }
  int c = pcoord[n];
  int cx = c & 255, cy = (c >> 8) & 255, cz = (c >> 16) & 255;
#pragma unroll
  for (int k = 0; k < 27; ++k) {
    int nx = cx + k / 9 - 1;
    int ny = cy + (k / 3) % 3 - 1;
    int nz = cz + k % 3 - 1;
    int id = NPTS;
    if (((unsigned)nx <= 64u) && ((unsigned)ny <= 64u) && ((unsigned)nz <= 64u)) {
      int v = m[(nx * 65 + ny) * 65 + nz];
      if (v >= 0) id = v;
    }
    nid[k * MPAD + n] = id;
  }
}

// ---------------- features fp32 -> bf16 (+ zero row at NPTS) ----------------
__global__ void conv_feat(const float* __restrict__ f, u16* __restrict__ o) {
  int q = blockIdx.x * 256 + threadIdx.x;       // quad index
  if (q >= (NPTS + 1) * 64) return;
  us4 r;
  if (q < NPTS * 64) {
    float4 v = ((const float4*)f)[q];
    r.x = f2bf(v.x); r.y = f2bf(v.y); r.z = f2bf(v.z); r.w = f2bf(v.w);
  } else {
    r.x = 0; r.y = 0; r.z = 0; r.w = 0;
  }
  ((us4*)o)[q] = r;
}

// -------- weight fp32 [27][ci][co] -> bf16 wt2[step(216)][kchunk(4)][co(256)][8]
__global__ void conv_wt2(const float* __restrict__ w, u16* __restrict__ wt2) {
  int u = blockIdx.x * 256 + threadIdx.x;       // < 27*65536
  int e = u & 7, row = (u >> 3) & 255, lk = (u >> 11) & 3, ks = (u >> 13) & 7, ko = u >> 16;
  int ci = ks * 32 + lk * 8 + e;
  wt2[u] = f2bf(w[ko * 65536 + ci * 256 + row]);
}

// ---------------- gather-GEMM: out[N,256] = sum_k gather(feat, nid_k) @ W_k ----------------
__device__ __forceinline__ void gload16(const void* g, unsigned int lds_off) {
  __builtin_amdgcn_global_load_lds(
      (__attribute__((address_space(1))) void*)(size_t)g,
      (__attribute__((address_space(3))) void*)(unsigned int)lds_off,
      16, 0, 0);
}

// Block tile 128x256, 4 waves, wave tile 128x64, BK=32, mfma 16x16x32.
// 3-deep LDS pipeline, counted vmcnt (never 0 in loop), raw s_barrier.
__global__ __launch_bounds__(256, 2) void gemm_kernel(const u16* __restrict__ feat,
                                                      const u16* __restrict__ wt,
                                                      const int* __restrict__ nid,
                                                      float* __restrict__ out) {
  __shared__ u16 As[3 * 4096];   // per buf 8KB: [row(128)][slot(4)][8e] (XOR-swizzled)
  __shared__ u16 Bs[3 * 8192];   // per buf 16KB: [kchunk(4)][co(256)][8e]
  int bm = blockIdx.x;
  int tid = threadIdx.x;
  int w = tid >> 6, l = tid & 63;     // 4 waves; wave w owns cols w*64..w*64+63
  int lm = l & 15, lk = l >> 4;

  unsigned A0 = (unsigned)(size_t)&As[0];
  unsigned B0 = (unsigned)(size_t)&Bs[0];
  const char* Asc = (const char*)&As[0];
  const char* Bsc = (const char*)&Bs[0];

  const char* featc = (const char*)feat;
  const char* wtc = (const char*)wt;

  // A staging: wave w stages rows w*32..w*32+31 via 2 insts (16 rows each,
  // 4 lanes/row, 16B/lane, coalesced 64B per row). XOR chunk swizzle on source.
  int rA = (w << 5) + (l >> 2);                // rows for inst1; inst2 = rA+16
  int gmA0 = bm * 128 + rA;
  int gmA1 = gmA0 + 16;
  // (rA+16)>>1 == rA>>1 (mod 4) -> both insts share cA
  int cA = (((l & 3) ^ ((rA >> 1) & 3)) << 4);
  // B staging: wave w stages kchunk w (4KB) via 4 linear insts
  size_t bSrc = (size_t)((w << 12) + (l << 4));
  // A ds_read swizzle: slot = lk ^ ((row>>1)&3); row dep reduces to lm bits
  int aswz = lk ^ ((lm >> 1) & 3);

  f32x4 acc[8][4];
#pragma unroll
  for (int m = 0; m < 8; ++m)
#pragma unroll
    for (int n = 0; n < 4; ++n) acc[m][n] = (f32x4){0.f, 0.f, 0.f, 0.f};

  int nv0 = nid[gmA0], nv1 = nid[gmA1];        // ko=0 gather rows
  int nv0n = nv0, nv1n = nv1;

  // prologue: stage steps 0,1 into bufs 0,1 (both ko=0)
  {
    const char* a0s = featc + ((size_t)nv0 << 9) + cA;
    const char* a1s = featc + ((size_t)nv1 << 9) + cA;
    gload16(a0s, A0 + (w << 11));
    gload16(a1s, A0 + (w << 11) + 1024);
    const char* bs0 = wtc + bSrc;
#pragma unroll
    for (int c = 0; c < 4; ++c) gload16(bs0 + (c << 10), B0 + (w << 12) + (c << 10));
    gload16(a0s + 64, A0 + 8192 + (w << 11));
    gload16(a1s + 64, A0 + 8192 + (w << 11) + 1024);
    const char* bs1 = wtc + 16384 + bSrc;
#pragma unroll
    for (int c = 0; c < 4; ++c) gload16(bs1 + (c << 10), B0 + 16384 + (w << 12) + (c << 10));
  }

  unsigned a0 = 0, a1 = 8192, a2 = 16384;       // A buf byte offsets
  unsigned b0 = 0, b1 = 16384, b2 = 32768;      // B buf byte offsets

  for (int ko = 0; ko < 27; ++ko) {
#pragma unroll
    for (int ks = 0; ks < 8; ++ks) {
      // ---- counted wait: retire exactly this step's 6 staging loads ----
      if (ko == 26 && ks == 7) {
        asm volatile("s_waitcnt vmcnt(0)" ::: "memory");
      } else if (ks == 1 && ko < 26) {
        asm volatile("s_waitcnt vmcnt(8)" ::: "memory");   // +2 boundary nid loads
      } else {
        asm volatile("s_waitcnt vmcnt(6)" ::: "memory");
      }
      __builtin_amdgcn_s_barrier();

      // ---- per-ko nid prefetch ----
      if (ks == 0 && ko < 26) {
        nv0n = nid[(ko + 1) * MPAD + gmA0];
        nv1n = nid[(ko + 1) * MPAD + gmA1];
      }

      // ---- stage step t+2 into bufs (a2,b2); loads stay in flight 2 steps ----
      if (!(ko == 26 && ks >= 6)) {
        int s0 = (ks >= 6) ? nv0n : nv0;       // t+2 crosses into ko+1 iff ks>=6
        int s1 = (ks >= 6) ? nv1n : nv1;
        int kb = ((ks + 2) & 7) << 6;
        const char* a0s = featc + ((size_t)s0 << 9) + kb + cA;
        const char* a1s = featc + ((size_t)s1 << 9) + kb + cA;
        gload16(a0s, A0 + a2 + (w << 11));
        gload16(a1s, A0 + a2 + (w << 11) + 1024);
        const char* bs = wtc + ((size_t)(ko * 8 + ks + 2) << 14) + bSrc;
#pragma unroll
        for (int c = 0; c < 4; ++c)
          gload16(bs + (c << 10), B0 + b2 + (w << 12) + (c << 10));
      }

      // ---- compute step t from bufs (a0,b0) ----
      const bf16x8* Av = (const bf16x8*)(Asc + a0);
      const bf16x8* Bv = (const bf16x8*)(Bsc + b0);
      bf16x8 bfr[4];
#pragma unroll
      for (int n = 0; n < 4; ++n) bfr[n] = Bv[(lk << 8) + (w << 6) + (n << 4) + lm];
#pragma unroll
      for (int h = 0; h < 2; ++h) {
        bf16x8 afr[4];
#pragma unroll
        for (int m4 = 0; m4 < 4; ++m4)
          afr[m4] = Av[(((h << 6) + (m4 << 4) + lm) << 2) + aswz];
        __builtin_amdgcn_s_setprio(1);
#pragma unroll
        for (int m4 = 0; m4 < 4; ++m4)
#pragma unroll
          for (int n = 0; n < 4; ++n)
            acc[h * 4 + m4][n] = __builtin_amdgcn_mfma_f32_16x16x32_bf16(
                afr[m4], bfr[n], acc[h * 4 + m4][n], 0, 0, 0);
        __builtin_amdgcn_s_setprio(0);
      }

      // ---- rotate buffers ----
      { unsigned t_ = a0; a0 = a1; a1 = a2; a2 = t_; }
      { unsigned t_ = b0; b0 = b1; b1 = b2; b2 = t_; }
    }
    nv0 = nv0n; nv1 = nv1n;
  }

  // epilogue: D row = m*16 + lk*4 + i, col = w*64 + n*16 + lm
#pragma unroll
  for (int m = 0; m < 8; ++m) {
#pragma unroll
    for (int i = 0; i < 4; ++i) {
      int gr2 = bm * 128 + (m << 4) + (lk << 2) + i;
      if (gr2 < NPTS) {
        float* po = out + (size_t)gr2 * 256 + (w << 6) + lm;
#pragma unroll
        for (int n = 0; n < 4; ++n) po[n << 4] = acc[m][n][i];
      }
    }
  }
}

extern "C" void kernel_launch(void* const* d_in, const int* in_sizes, int n_in,
                              void* d_out, int out_size, void* d_ws, size_t ws_size,
                              hipStream_t stream) {
  const float* features = (const float*)d_in[0];
  const float* depth = (const float*)d_in[1];
  const float* weight = (const float*)d_in[2];
  float* out = (float*)d_out;
  char* ws = (char*)d_ws;

  // ws layout (256B aligned)
  int* idx_map = (int*)(ws + 0);              // 274625 ints
  int* pcoord  = (int*)(ws + 1098752);        // 65552 ints
  int* nid     = (int*)(ws + 1361152);        // 27*65664 ints
  u16* feat_bf = (u16*)(ws + 8452864);        // (65552+1)*256 bf16
  u16* wt_bf   = (u16*)(ws + 42016256);       // 27*65536 bf16 (pre-arranged)
  // total ~45.6 MB

  coords_kernel<<<16, 256, 0, stream>>>(depth, pcoord);
  init_idx<<<(NVOX + 255) / 256, 256, 0, stream>>>(idx_map);
  scatter_idx<<<(NPTS + 255) / 256, 256, 0, stream>>>(pcoord, idx_map);
  nbr_kernel<<<(MPAD + 255) / 256, 256, 0, stream>>>(pcoord, idx_map, nid);
  conv_feat<<<((NPTS + 1) * 64 + 255) / 256, 256, 0, stream>>>(features, feat_bf);
  conv_wt2<<<27 * 65536 / 256, 256, 0, stream>>>(weight, wt_bf);
  gemm_kernel<<<513, 256, 0, stream>>>(feat_bf, wt_bf, nid, out);
}